// Round 13
// baseline (288.319 us; speedup 1.0000x reference)
//
#include <hip/hip_runtime.h>
#include <cstdint>

#define B_ 512
#define N_ 150
#define NT 640
#define PPS 152            // per-b: 150 psi (log2 units) + nsc
#define C1f 144.26950408889634f    // log2(e)/eps, eps=0.01
#define LN2f 0.69314718055994531f
#define SIGMAf 1.0e-4f
#define INV_N (1.0f/150.0f)

// raw hardware transcendentals (1-ULP v_exp_f32 / v_log_f32)
#define EXP2R(x) __builtin_amdgcn_exp2f(x)
#define LOG2R(x) __builtin_amdgcn_logf(x)

// DPP quad-perm reduces (VALU pipe): xor1 = 0xB1, xor2 = 0x4E
#define DPPF(v, c) __int_as_float(__builtin_amdgcn_update_dpp( \
    __float_as_int(v), __float_as_int(v), (c), 0xF, 0xF, false))
#define RED4_ADD(v)  { v = v + DPPF(v, 0xB1); v = v + DPPF(v, 0x4E); }

#define REP10(X) X(0) X(1) X(2) X(3) X(4) X(5) X(6) X(7) X(8) X(9)

// Threefry-2x32, 20 rounds, exactly as JAX's threefry2x32 lowering.
__host__ __device__ __forceinline__ void tf2x32(uint32_t k0, uint32_t k1,
                                                uint32_t x0, uint32_t x1,
                                                uint32_t& o0, uint32_t& o1) {
  uint32_t ks2 = k0 ^ k1 ^ 0x1BD11BDAu;
  x0 += k0; x1 += k1;
#define TFR(r) { x0 += x1; x1 = (x1 << r) | (x1 >> (32 - r)); x1 ^= x0; }
  TFR(13) TFR(15) TFR(26) TFR(6)
  x0 += k1;  x1 += ks2 + 1u;
  TFR(17) TFR(29) TFR(16) TFR(24)
  x0 += ks2; x1 += k0 + 2u;
  TFR(13) TFR(15) TFR(26) TFR(6)
  x0 += k0;  x1 += k1 + 3u;
  TFR(17) TFR(29) TFR(16) TFR(24)
  x0 += k1;  x1 += ks2 + 4u;
  TFR(13) TFR(15) TFR(26) TFR(6)
  x0 += ks2; x1 += k0 + 5u;
#undef TFR
  o0 = x0; o1 = x1;
}

__device__ __forceinline__ uint32_t jax_bits(uint32_t k0, uint32_t k1, uint32_t p) {
  uint32_t a, b; tf2x32(k0, k1, 0u, p, a, b);   // partitionable: counter (0, p)
  return a ^ b;
}

// ==== Kernel 1: Sinkhorn, static K, TWO samples per block ===================
// R8's exact structure per sample; grid 256 (1 block/CU, single generation).
// thread (rg = tid/40, cg = tid%40) owns rows rg*10..+9, cols cg*4..+3 of BOTH
// samples' K. The 4 barriers/iter are shared by both samples; each barrier
// interval carries 2x independent FMA chains (ILP) vs R8's 2-block overlap.
__global__ __launch_bounds__(NT, 3) void cfm_ot_kernel(
    const float* __restrict__ x1g, const float* __restrict__ x0g,
    float* __restrict__ pp)
{
  __shared__ float x1A[480], x0A[480], x1B[480], x0B[480];
  __shared__ __align__(16) float colpA[16 * 164], colpB[16 * 164];
  __shared__ float rowqA[160 * 11], rowqB[160 * 11];
  __shared__ __align__(16) float vhatA[160], vhatB[160];
  __shared__ float uhatA[160], uhatB[160];
  __shared__ float red[32];
  float4* colpA4 = (float4*)colpA;   // row stride 41
  float4* colpB4 = (float4*)colpB;
  float4* vhatA4 = (float4*)vhatA;
  float4* vhatB4 = (float4*)vhatB;

  const int b0   = 2 * blockIdx.x;
  const int b1   = b0 + 1;
  const int tid  = threadIdx.x;
  const int lane = tid & 63;
  const int wid  = tid >> 6;
  const int rg   = tid / 40;        // 0..15
  const int cg   = tid - rg * 40;   // 0..39
  const int q    = tid & 3;         // == cg&3 (40 % 4 == 0)
  const int cgq  = cg >> 2;         // 0..9
  const int rbase = rg * 10;
  const int cbase = cg * 4;

  if (tid < 480) {
    x1A[tid] = (tid < 450) ? x1g[b0 * 450 + tid] : 0.f;
    x0A[tid] = (tid < 450) ? x0g[b0 * 450 + tid] : 0.f;
    x1B[tid] = (tid < 450) ? x1g[b1 * 450 + tid] : 0.f;
    x0B[tid] = (tid < 450) ? x0g[b1 * 450 + tid] : 0.f;
  }
  if (tid < 160) { uhatA[tid] = 1.0f; uhatB[tid] = 1.0f; }
  __syncthreads();

  // ---- distances into named tile regs (both samples), per-sample max ----
  float4 ktA0, ktA1, ktA2, ktA3, ktA4, ktA5, ktA6, ktA7, ktA8, ktA9;
  float4 ktB0, ktB1, ktB2, ktB3, ktB4, ktB5, ktB6, ktB7, ktB8, ktB9;
  float lmaxA = 0.f, lmaxB = 0.f;
#define DISTS(S) { \
    const float c0 = x1##S[cbase * 3 + 0], c1 = x1##S[cbase * 3 + 1], c2 = x1##S[cbase * 3 + 2]; \
    const float d0 = x1##S[cbase * 3 + 3], d1 = x1##S[cbase * 3 + 4], d2 = x1##S[cbase * 3 + 5]; \
    const float e0 = x1##S[cbase * 3 + 6], e1 = x1##S[cbase * 3 + 7], e2 = x1##S[cbase * 3 + 8]; \
    const float f0 = x1##S[cbase * 3 + 9], f1 = x1##S[cbase * 3 + 10], f2 = x1##S[cbase * 3 + 11]; \
    _Pragma("unroll") \
    for (int r = 0; r < 10; ++r) { \
      const int row = rbase + r; \
      const float rx = x0##S[row * 3 + 0], ry = x0##S[row * 3 + 1], rz = x0##S[row * 3 + 2]; \
      float dx, dy, dz, d; float t0_, t1_, t2_, t3_; \
      dx = rx - c0; dy = ry - c1; dz = rz - c2; \
      d = fmaf(dz, dz, fmaf(dy, dy, dx * dx)); \
      t0_ = (row < N_ && cbase + 0 < N_) ? d : 0.f; \
      dx = rx - d0; dy = ry - d1; dz = rz - d2; \
      d = fmaf(dz, dz, fmaf(dy, dy, dx * dx)); \
      t1_ = (row < N_ && cbase + 1 < N_) ? d : 0.f; \
      dx = rx - e0; dy = ry - e1; dz = rz - e2; \
      d = fmaf(dz, dz, fmaf(dy, dy, dx * dx)); \
      t2_ = (row < N_ && cbase + 2 < N_) ? d : 0.f; \
      dx = rx - f0; dy = ry - f1; dz = rz - f2; \
      d = fmaf(dz, dz, fmaf(dy, dy, dx * dx)); \
      t3_ = (row < N_ && cbase + 3 < N_) ? d : 0.f; \
      lmax##S = fmaxf(lmax##S, fmaxf(fmaxf(t0_, t1_), fmaxf(t2_, t3_))); \
      switch (r) { \
        case 0: kt##S##0 = make_float4(t0_, t1_, t2_, t3_); break; \
        case 1: kt##S##1 = make_float4(t0_, t1_, t2_, t3_); break; \
        case 2: kt##S##2 = make_float4(t0_, t1_, t2_, t3_); break; \
        case 3: kt##S##3 = make_float4(t0_, t1_, t2_, t3_); break; \
        case 4: kt##S##4 = make_float4(t0_, t1_, t2_, t3_); break; \
        case 5: kt##S##5 = make_float4(t0_, t1_, t2_, t3_); break; \
        case 6: kt##S##6 = make_float4(t0_, t1_, t2_, t3_); break; \
        case 7: kt##S##7 = make_float4(t0_, t1_, t2_, t3_); break; \
        case 8: kt##S##8 = make_float4(t0_, t1_, t2_, t3_); break; \
        case 9: kt##S##9 = make_float4(t0_, t1_, t2_, t3_); break; \
      } } }
  DISTS(A)
  DISTS(B)
#undef DISTS
  #pragma unroll
  for (int off = 1; off < 64; off <<= 1) {
    lmaxA = fmaxf(lmaxA, __shfl_xor(lmaxA, off));
    lmaxB = fmaxf(lmaxB, __shfl_xor(lmaxB, off));
  }
  if (lane == 0) { red[wid] = lmaxA; red[10 + wid] = lmaxB; }
  __syncthreads();
  if (tid == 0) {
    float mA = red[0], mB = red[10];
    #pragma unroll
    for (int w = 1; w < 10; ++w) { mA = fmaxf(mA, red[w]); mB = fmaxf(mB, red[10 + w]); }
    red[30] = -C1f / mA;
    red[31] = -C1f / mB;
  }
  __syncthreads();
  const float nscA = red[30];
  const float nscB = red[31];

  // ---- K = exp2(nsc * D); pads -> 0 ----
#define TOK(S, k) { \
    const int rA0 = rbase + k; (void)rA0; \
    kt##S##k.x = (rbase + k < N_ + 0 || true) ? kt##S##k.x : 0.f; }
#undef TOK
#define TOKR(S, k) { \
    const int row = rbase + k; \
    kt##S##k.x = (row < N_ && cbase + 0 < N_) ? EXP2R(nsc##S * kt##S##k.x) : 0.f; \
    kt##S##k.y = (row < N_ && cbase + 1 < N_) ? EXP2R(nsc##S * kt##S##k.y) : 0.f; \
    kt##S##k.z = (row < N_ && cbase + 2 < N_) ? EXP2R(nsc##S * kt##S##k.z) : 0.f; \
    kt##S##k.w = (row < N_ && cbase + 3 < N_) ? EXP2R(nsc##S * kt##S##k.w) : 0.f; }
#define TOKA(k) TOKR(A, k)
#define TOKB(k) TOKR(B, k)
  REP10(TOKA)
  REP10(TOKB)
#undef TOKA
#undef TOKB
#undef TOKR

  // ---- 100 iterations; K read-only; 4 barriers shared by 2 samples ----
  for (int it = 0; it < 100; ++it) {
    // phase A partials: col sums of K^T u (both samples)
    {
      float4 pA = make_float4(0.f, 0.f, 0.f, 0.f);
      float4 pB = make_float4(0.f, 0.f, 0.f, 0.f);
#define COLA(k) { \
      const float urA = uhatA[rbase + k]; \
      const float urB = uhatB[rbase + k]; \
      pA.x = fmaf(ktA##k.x, urA, pA.x); \
      pA.y = fmaf(ktA##k.y, urA, pA.y); \
      pA.z = fmaf(ktA##k.z, urA, pA.z); \
      pA.w = fmaf(ktA##k.w, urA, pA.w); \
      pB.x = fmaf(ktB##k.x, urB, pB.x); \
      pB.y = fmaf(ktB##k.y, urB, pB.y); \
      pB.z = fmaf(ktB##k.z, urB, pB.z); \
      pB.w = fmaf(ktB##k.w, urB, pB.w); }
      REP10(COLA)
#undef COLA
      colpA4[rg * 41 + cg] = pA;
      colpB4[rg * 41 + cg] = pB;
    }
    __syncthreads();
    // finalize colsum -> vhat (sample A: waves 0-2; sample B: waves 5-7)
    if (tid < 160) {
      float s = 0.f;
      #pragma unroll
      for (int k = 0; k < 16; ++k) s += colpA[k * 164 + tid];
      vhatA[tid] = __builtin_amdgcn_rcpf(fmaxf(s, 1e-37f)) * INV_N;
    } else if (tid >= 320 && tid < 480) {
      const int c = tid - 320;
      float s = 0.f;
      #pragma unroll
      for (int k = 0; k < 16; ++k) s += colpB[k * 164 + c];
      vhatB[c] = __builtin_amdgcn_rcpf(fmaxf(s, 1e-37f)) * INV_N;
    }
    __syncthreads();
    // phase B: row partials of K v (quad reduce), both samples
    {
      const float4 vA = vhatA4[cg];
      const float4 vB = vhatB4[cg];
#define ROWB(k) { \
      float rpA = ktA##k.x * vA.x; \
      rpA = fmaf(ktA##k.y, vA.y, rpA); \
      rpA = fmaf(ktA##k.z, vA.z, rpA); \
      rpA = fmaf(ktA##k.w, vA.w, rpA); \
      float rpB = ktB##k.x * vB.x; \
      rpB = fmaf(ktB##k.y, vB.y, rpB); \
      rpB = fmaf(ktB##k.z, vB.z, rpB); \
      rpB = fmaf(ktB##k.w, vB.w, rpB); \
      RED4_ADD(rpA) \
      RED4_ADD(rpB) \
      if (q == 0) { \
        rowqA[(rbase + k) * 11 + cgq] = rpA; \
        rowqB[(rbase + k) * 11 + cgq] = rpB; } }
      REP10(ROWB)
#undef ROWB
    }
    __syncthreads();
    // finalize rowsum -> uhat
    if (tid < 160) {
      float s = 0.f;
      #pragma unroll
      for (int u = 0; u < 10; ++u) s += rowqA[tid * 11 + u];
      uhatA[tid] = __builtin_amdgcn_rcpf(fmaxf(s, 1e-37f)) * INV_N;
    } else if (tid >= 320 && tid < 480) {
      const int c = tid - 320;
      float s = 0.f;
      #pragma unroll
      for (int u = 0; u < 10; ++u) s += rowqB[c * 11 + u];
      uhatB[c] = __builtin_amdgcn_rcpf(fmaxf(s, 1e-37f)) * INV_N;
    }
    __syncthreads();
  }

  // ---- psi = log2(v_final) + nsc, both samples ----
  if (tid < N_) {
    pp[b0 * PPS + tid] = LOG2R(vhatA[tid]);
    pp[b1 * PPS + tid] = LOG2R(vhatB[tid]);
  }
  if (tid == 0) {
    pp[b0 * PPS + 150] = nscA;
    pp[b1 * PPS + 150] = nscB;
  }
}

// ======================= Kernel 2: sampling + MLP loss ======================
__global__ __launch_bounds__(NT) void cfm_sample_kernel(
    const float* __restrict__ x1g, const float* __restrict__ maskg,
    const float* __restrict__ tg, const float* __restrict__ x0g,
    const float* __restrict__ epsg,
    const float* __restrict__ W1, const float* __restrict__ b1,
    const float* __restrict__ W2, const float* __restrict__ b2,
    const float* __restrict__ pp, float* __restrict__ partials,
    uint32_t kj0, uint32_t kj1, uint32_t k1r0, uint32_t k1r1,
    uint32_t k2r0, uint32_t k2r1)
{
  __shared__ float x1L[450], x0L[450], psiS[152], mskS[152];
  __shared__ float yu[150 * 9];   // per-n: y0,y1,y2,u0,u1,u2,mot (stride 9)
  __shared__ float red[16];
  __shared__ int   iselS[152];

  const int b    = blockIdx.x;
  const int tid  = threadIdx.x;
  const int lane = tid & 63;
  const int wid  = tid >> 6;

  if (tid < 450) {
    x1L[tid] = x1g[b * 450 + tid];
    x0L[tid] = x0g[b * 450 + tid];
  }
  if (tid < N_) {
    psiS[tid] = pp[b * PPS + tid];
    mskS[tid] = maskg[b * 150 + tid];
    // i = randint(ki,(B,N),0,150): ((hi%150)*(2^32%150) + lo%150) % 150
    const uint32_t p = (uint32_t)(b * N_ + tid);
    const uint32_t hb = jax_bits(k1r0, k1r1, p);
    const uint32_t lb = jax_bits(k2r0, k2r1, p);
    iselS[tid] = (int)(((hb % 150u) * 46u + (lb % 150u)) % 150u);
  }
  const float nsc = pp[b * PPS + 150];
  const float tb  = tg[b];
  __syncthreads();

  // ---- S1: gumbel argmax per sample (wave per n), store y/u/mot ----
  for (int n = wid; n < N_; n += 10) {
    const uint32_t p = (uint32_t)(b * N_ + n);
    const int isel = iselS[n];
    const float xi0 = x0L[isel * 3 + 0], xi1 = x0L[isel * 3 + 1], xi2 = x0L[isel * 3 + 2];

    float best = -1e30f; int bestk = 0x7fffffff;
    #pragma unroll
    for (int c2 = 0; c2 < 3; ++c2) {
      const int k = lane + 64 * c2;
      if (k < N_) {
        const uint32_t bits = jax_bits(kj0, kj1, p * 150u + (uint32_t)k);
        float u = __uint_as_float((bits >> 9) | 0x3F800000u) - 1.0f;
        u = fmaxf(u, 1.17549435e-38f);
        const float nlu = -LN2f * LOG2R(u);
        const float g = -LN2f * LOG2R(nlu);
        const float dx = xi0 - x1L[k * 3 + 0];
        const float dy = xi1 - x1L[k * 3 + 1];
        const float dz = xi2 - x1L[k * 3 + 2];
        const float d2 = fmaf(dz, dz, fmaf(dy, dy, dx * dx));
        const float val = fmaf(psiS[k] + nsc * d2, LN2f, g);  // phi_i const over k
        if (val > best || (val == best && k < bestk)) { best = val; bestk = k; }
      }
    }
    #pragma unroll
    for (int off = 1; off < 64; off <<= 1) {
      const float ov = __shfl_xor(best, off);
      const int   ok = __shfl_xor(bestk, off);
      if (ov > best || (ov == best && ok < bestk)) { best = ov; bestk = ok; }
    }
    if (lane == 0) {
      const int j = bestk;
      const float mot = mskS[j];
      const float q0 = x1L[j * 3 + 0], q1 = x1L[j * 3 + 1], q2 = x1L[j * 3 + 2];
      const float omt = 1.f - tb;
      yu[n * 9 + 0] = xi0 * tb + q0 * omt + SIGMAf * epsg[b * 450 + n * 3 + 0];
      yu[n * 9 + 1] = xi1 * tb + q1 * omt + SIGMAf * epsg[b * 450 + n * 3 + 1];
      yu[n * 9 + 2] = xi2 * tb + q2 * omt + SIGMAf * epsg[b * 450 + n * 3 + 2];
      yu[n * 9 + 3] = (xi0 - q0) * mot;
      yu[n * 9 + 4] = (xi1 - q1) * mot;
      yu[n * 9 + 5] = (xi2 - q2) * mot;
      yu[n * 9 + 6] = mot;
    }
  }
  __syncthreads();

  // ---- S2: MLP, lane = sample, hd loop uniform -> scalar W loads ----
  float loss = 0.f;
  if (wid < 3) {
    const int n = wid * 64 + lane;
    if (n < N_) {
      const float y0 = yu[n * 9 + 0], y1 = yu[n * 9 + 1], y2 = yu[n * 9 + 2];
      const float u0 = yu[n * 9 + 3], u1 = yu[n * 9 + 4], u2 = yu[n * 9 + 5];
      const float mot = yu[n * 9 + 6];
      float a0 = 0.f, a1 = 0.f, a2 = 0.f;
      #pragma unroll 4
      for (int hd = 0; hd < 512; ++hd) {
        float z = b1[hd];
        z = fmaf(y0, W1[hd],        z);
        z = fmaf(y1, W1[512 + hd],  z);
        z = fmaf(y2, W1[1024 + hd], z);
        z = fmaf(tb, W1[1536 + hd], z);
        const float zc = fmaf(0.044715f * z, z * z, z);
        const float e2 = EXP2R(-2.3022082062161855f * zc);
        const float ge = z * __builtin_amdgcn_rcpf(1.f + e2);
        a0 = fmaf(ge, W2[hd * 3 + 0], a0);
        a1 = fmaf(ge, W2[hd * 3 + 1], a1);
        a2 = fmaf(ge, W2[hd * 3 + 2], a2);
      }
      const float v0 = (a0 + b2[0]) * mot;
      const float v1 = (a1 + b2[1]) * mot;
      const float v2 = (a2 + b2[2]) * mot;
      const float d0 = v0 - u0, d1 = v1 - u1, d2 = v2 - u2;
      loss = fmaf(d2, d2, fmaf(d1, d1, d0 * d0));
    }
    #pragma unroll
    for (int off = 1; off < 64; off <<= 1) loss += __shfl_xor(loss, off);
    if (lane == 0) red[wid] = loss;
  }
  __syncthreads();
  if (tid == 0) partials[b] = red[0] + red[1] + red[2];
}

__global__ void cfm_reduce_kernel(const float* __restrict__ partials,
                                  float* __restrict__ out) {
  const int tid = threadIdx.x;   // 64 threads
  float s = 0.f;
  #pragma unroll
  for (int q = 0; q < 8; ++q) s += partials[tid + 64 * q];
  #pragma unroll
  for (int off = 1; off < 64; off <<= 1) s += __shfl_xor(s, off);
  if (tid == 0) out[0] = s * (1.0f / 230400.0f);
}

extern "C" void kernel_launch(void* const* d_in, const int* in_sizes, int n_in,
                              void* d_out, int out_size, void* d_ws, size_t ws_size,
                              hipStream_t stream) {
  (void)in_sizes; (void)n_in; (void)out_size; (void)ws_size;
  const float* x    = (const float*)d_in[0];
  const float* mask = (const float*)d_in[1];
  const float* t    = (const float*)d_in[2];
  const float* x0n  = (const float*)d_in[3];
  const float* epsn = (const float*)d_in[4];
  const float* W1   = (const float*)d_in[5];
  const float* b1   = (const float*)d_in[6];
  const float* W2   = (const float*)d_in[7];
  const float* b2   = (const float*)d_in[8];
  float* out = (float*)d_out;

  float* pp       = (float*)d_ws;              // 512 * 152 floats
  float* partials = pp + B_ * PPS;             // 512 floats

  uint32_t ki0, ki1, kj0, kj1, k1r0, k1r1, k2r0, k2r1;
  tf2x32(0u, 42u, 0u, 0u, ki0, ki1);
  tf2x32(0u, 42u, 0u, 1u, kj0, kj1);
  tf2x32(ki0, ki1, 0u, 0u, k1r0, k1r1);
  tf2x32(ki0, ki1, 0u, 1u, k2r0, k2r1);

  cfm_ot_kernel<<<B_ / 2, NT, 0, stream>>>(x, x0n, pp);
  cfm_sample_kernel<<<B_, NT, 0, stream>>>(x, mask, t, x0n, epsn, W1, b1, W2, b2,
                                           pp, partials,
                                           kj0, kj1, k1r0, k1r1, k2r0, k2r1);
  cfm_reduce_kernel<<<1, 64, 0, stream>>>(partials, out);
}

// Round 14
// 263.559 us; speedup vs baseline: 1.0939x; 1.0939x over previous
//
#include <hip/hip_runtime.h>
#include <cstdint>

#define B_ 512
#define N_ 150
#define NT 640
#define PPS 152            // per-b: 150 psi (log2 units) + nsc
#define C1f 144.26950408889634f    // log2(e)/eps, eps=0.01
#define LN2f 0.69314718055994531f
#define SIGMAf 1.0e-4f
#define INV_N (1.0f/150.0f)

// raw hardware transcendentals (1-ULP v_exp_f32 / v_log_f32)
#define EXP2R(x) __builtin_amdgcn_exp2f(x)
#define LOG2R(x) __builtin_amdgcn_logf(x)

// DPP quad-perm reduces (VALU pipe): xor1 = 0xB1, xor2 = 0x4E
#define DPPF(v, c) __int_as_float(__builtin_amdgcn_update_dpp( \
    __float_as_int(v), __float_as_int(v), (c), 0xF, 0xF, false))
#define RED4_ADD(v)  { v = v + DPPF(v, 0xB1); v = v + DPPF(v, 0x4E); }

#define REP10(X) X(0) X(1) X(2) X(3) X(4) X(5) X(6) X(7) X(8) X(9)

// Threefry-2x32, 20 rounds, exactly as JAX's threefry2x32 lowering.
__host__ __device__ __forceinline__ void tf2x32(uint32_t k0, uint32_t k1,
                                                uint32_t x0, uint32_t x1,
                                                uint32_t& o0, uint32_t& o1) {
  uint32_t ks2 = k0 ^ k1 ^ 0x1BD11BDAu;
  x0 += k0; x1 += k1;
#define TFR(r) { x0 += x1; x1 = (x1 << r) | (x1 >> (32 - r)); x1 ^= x0; }
  TFR(13) TFR(15) TFR(26) TFR(6)
  x0 += k1;  x1 += ks2 + 1u;
  TFR(17) TFR(29) TFR(16) TFR(24)
  x0 += ks2; x1 += k0 + 2u;
  TFR(13) TFR(15) TFR(26) TFR(6)
  x0 += k0;  x1 += k1 + 3u;
  TFR(17) TFR(29) TFR(16) TFR(24)
  x0 += k1;  x1 += ks2 + 4u;
  TFR(13) TFR(15) TFR(26) TFR(6)
  x0 += ks2; x1 += k0 + 5u;
#undef TFR
  o0 = x0; o1 = x1;
}

__device__ __forceinline__ uint32_t jax_bits(uint32_t k0, uint32_t k1, uint32_t p) {
  uint32_t a, b; tf2x32(k0, k1, 0u, p, a, b);   // partitionable: counter (0, p)
  return a ^ b;
}

// ==== Kernel 1: Sinkhorn, classic scaled form (R8 base), LDS-instr diet =====
// thread (rg = tid/40, cg = tid%40) owns rows rg*10..+9, cols cg*4..+3.
// Change 1: uhat in padded stride-12 rows -> phase-A u loads = b128,b128,b64.
// Change 2: rowq transposed (stride 162) -> phase-B stores = 5x float2.
// Math and sum order bit-identical to R8 (183us).
__global__ __launch_bounds__(NT, 5) void cfm_ot_kernel(
    const float* __restrict__ x1g, const float* __restrict__ x0g,
    float* __restrict__ pp)
{
  __shared__ float x1L[480], x0L[480];
  __shared__ __align__(16) float colp[16 * 164];   // [rg][164] col partials
  __shared__ __align__(16) float rowqT[10 * 162];  // [cgq][162] row partials
  __shared__ __align__(16) float vhat[160];        // v
  __shared__ __align__(16) float uhatP[16 * 12];   // u, padded rows of 12
  __shared__ float red[16];
  float4* colp4 = (float4*)colp;    // row stride 41
  float4* vhat4 = (float4*)vhat;

  const int b    = blockIdx.x;
  const int tid  = threadIdx.x;
  const int lane = tid & 63;
  const int wid  = tid >> 6;
  const int rg   = tid / 40;        // 0..15
  const int cg   = tid - rg * 40;   // 0..39
  const int q    = tid & 3;         // == cg&3 (40 % 4 == 0)
  const int cgq  = cg >> 2;         // 0..9
  const int rbase = rg * 10;
  const int cbase = cg * 4;

  if (tid < 480) {
    x1L[tid] = (tid < 450) ? x1g[b * 450 + tid] : 0.f;
    x0L[tid] = (tid < 450) ? x0g[b * 450 + tid] : 0.f;
  }
  if (tid < 192) uhatP[tid] = 1.0f;       // u0 = 1 (f = 0); pads harmless
  __syncthreads();

  // ---- distances into named tile regs, track block max ----
  float4 kt0, kt1, kt2, kt3, kt4, kt5, kt6, kt7, kt8, kt9;
  float lmax = 0.f;
  {
    const float c0 = x1L[cbase * 3 + 0], c1 = x1L[cbase * 3 + 1], c2 = x1L[cbase * 3 + 2];
    const float d0 = x1L[cbase * 3 + 3], d1 = x1L[cbase * 3 + 4], d2 = x1L[cbase * 3 + 5];
    const float e0 = x1L[cbase * 3 + 6], e1 = x1L[cbase * 3 + 7], e2 = x1L[cbase * 3 + 8];
    const float f0 = x1L[cbase * 3 + 9], f1 = x1L[cbase * 3 + 10], f2 = x1L[cbase * 3 + 11];
#define DIST(r) { \
    const int row = rbase + r; \
    const float rx = x0L[row * 3 + 0], ry = x0L[row * 3 + 1], rz = x0L[row * 3 + 2]; \
    float dx, dy, dz, d; \
    dx = rx - c0; dy = ry - c1; dz = rz - c2; \
    d = fmaf(dz, dz, fmaf(dy, dy, dx * dx)); \
    kt##r.x = (row < N_ && cbase + 0 < N_) ? d : 0.f; \
    dx = rx - d0; dy = ry - d1; dz = rz - d2; \
    d = fmaf(dz, dz, fmaf(dy, dy, dx * dx)); \
    kt##r.y = (row < N_ && cbase + 1 < N_) ? d : 0.f; \
    dx = rx - e0; dy = ry - e1; dz = rz - e2; \
    d = fmaf(dz, dz, fmaf(dy, dy, dx * dx)); \
    kt##r.z = (row < N_ && cbase + 2 < N_) ? d : 0.f; \
    dx = rx - f0; dy = ry - f1; dz = rz - f2; \
    d = fmaf(dz, dz, fmaf(dy, dy, dx * dx)); \
    kt##r.w = (row < N_ && cbase + 3 < N_) ? d : 0.f; \
    lmax = fmaxf(lmax, fmaxf(fmaxf(kt##r.x, kt##r.y), fmaxf(kt##r.z, kt##r.w))); }
    REP10(DIST)
#undef DIST
  }
  #pragma unroll
  for (int off = 1; off < 64; off <<= 1) lmax = fmaxf(lmax, __shfl_xor(lmax, off));
  if (lane == 0) red[wid] = lmax;
  __syncthreads();
  if (tid == 0) {
    float m = red[0];
    #pragma unroll
    for (int w = 1; w < 10; ++w) m = fmaxf(m, red[w]);
    red[15] = -C1f / m;
  }
  __syncthreads();
  const float nsc = red[15];

  // ---- K = exp2(nsc * D); pads -> 0 ----
#define TOK(r) { \
    const int row = rbase + r; \
    kt##r.x = (row < N_ && cbase + 0 < N_) ? EXP2R(nsc * kt##r.x) : 0.f; \
    kt##r.y = (row < N_ && cbase + 1 < N_) ? EXP2R(nsc * kt##r.y) : 0.f; \
    kt##r.z = (row < N_ && cbase + 2 < N_) ? EXP2R(nsc * kt##r.z) : 0.f; \
    kt##r.w = (row < N_ && cbase + 3 < N_) ? EXP2R(nsc * kt##r.w) : 0.f; }
  REP10(TOK)
#undef TOK

  // ---- 100 iterations; K read-only, only u/v updated ----
  for (int it = 0; it < 100; ++it) {
    // phase A: col partials of K^T u; u loaded as b128+b128+b64 (padded rows)
    {
      const float4 ua = *(const float4*)&uhatP[rg * 12];
      const float4 ub = *(const float4*)&uhatP[rg * 12 + 4];
      const float2 uc = *(const float2*)&uhatP[rg * 12 + 8];
      float4 p4 = make_float4(0.f, 0.f, 0.f, 0.f);
#define COLA(k, uu) { \
      p4.x = fmaf(kt##k.x, uu, p4.x); \
      p4.y = fmaf(kt##k.y, uu, p4.y); \
      p4.z = fmaf(kt##k.z, uu, p4.z); \
      p4.w = fmaf(kt##k.w, uu, p4.w); }
      COLA(0, ua.x) COLA(1, ua.y) COLA(2, ua.z) COLA(3, ua.w)
      COLA(4, ub.x) COLA(5, ub.y) COLA(6, ub.z) COLA(7, ub.w)
      COLA(8, uc.x) COLA(9, uc.y)
#undef COLA
      colp4[rg * 41 + cg] = p4;
    }
    __syncthreads();
    if (tid < 160) {
      float s = 0.f;
      #pragma unroll
      for (int k = 0; k < 16; ++k) s += colp[k * 164 + tid];
      vhat[tid] = __builtin_amdgcn_rcpf(fmaxf(s, 1e-37f)) * INV_N;
    }
    __syncthreads();
    // phase B: row partials of K v; quad reduce; 5x float2 stores (transposed)
    {
      const float4 vv = vhat4[cg];
#define ROWB(k) \
      float rp##k = kt##k.x * vv.x; \
      rp##k = fmaf(kt##k.y, vv.y, rp##k); \
      rp##k = fmaf(kt##k.z, vv.z, rp##k); \
      rp##k = fmaf(kt##k.w, vv.w, rp##k); \
      RED4_ADD(rp##k)
      REP10(ROWB)
#undef ROWB
      if (q == 0) {
        const int rb2 = cgq * 162 + rbase;
        *(float2*)&rowqT[rb2 + 0] = make_float2(rp0, rp1);
        *(float2*)&rowqT[rb2 + 2] = make_float2(rp2, rp3);
        *(float2*)&rowqT[rb2 + 4] = make_float2(rp4, rp5);
        *(float2*)&rowqT[rb2 + 6] = make_float2(rp6, rp7);
        *(float2*)&rowqT[rb2 + 8] = make_float2(rp8, rp9);
      }
    }
    __syncthreads();
    if (tid < 160) {
      float s = 0.f;
      #pragma unroll
      for (int u = 0; u < 10; ++u) s += rowqT[u * 162 + tid];
      const float uh = __builtin_amdgcn_rcpf(fmaxf(s, 1e-37f)) * INV_N;
      const int g = tid / 10;
      uhatP[g * 12 + (tid - g * 10)] = uh;
    }
    __syncthreads();
  }

  // ---- psi = log2(v_final) + nsc ----
  if (tid < N_) pp[b * PPS + tid] = LOG2R(vhat[tid]);
  if (tid == 0) pp[b * PPS + 150] = nsc;
}

// ======================= Kernel 2: sampling + MLP loss ======================
__global__ __launch_bounds__(NT) void cfm_sample_kernel(
    const float* __restrict__ x1g, const float* __restrict__ maskg,
    const float* __restrict__ tg, const float* __restrict__ x0g,
    const float* __restrict__ epsg,
    const float* __restrict__ W1, const float* __restrict__ b1,
    const float* __restrict__ W2, const float* __restrict__ b2,
    const float* __restrict__ pp, float* __restrict__ partials,
    uint32_t kj0, uint32_t kj1, uint32_t k1r0, uint32_t k1r1,
    uint32_t k2r0, uint32_t k2r1)
{
  __shared__ float x1L[450], x0L[450], psiS[152], mskS[152];
  __shared__ float yu[150 * 9];   // per-n: y0,y1,y2,u0,u1,u2,mot (stride 9)
  __shared__ float red[16];
  __shared__ int   iselS[152];

  const int b    = blockIdx.x;
  const int tid  = threadIdx.x;
  const int lane = tid & 63;
  const int wid  = tid >> 6;

  if (tid < 450) {
    x1L[tid] = x1g[b * 450 + tid];
    x0L[tid] = x0g[b * 450 + tid];
  }
  if (tid < N_) {
    psiS[tid] = pp[b * PPS + tid];
    mskS[tid] = maskg[b * 150 + tid];
    // i = randint(ki,(B,N),0,150): ((hi%150)*(2^32%150) + lo%150) % 150
    const uint32_t p = (uint32_t)(b * N_ + tid);
    const uint32_t hb = jax_bits(k1r0, k1r1, p);
    const uint32_t lb = jax_bits(k2r0, k2r1, p);
    iselS[tid] = (int)(((hb % 150u) * 46u + (lb % 150u)) % 150u);
  }
  const float nsc = pp[b * PPS + 150];
  const float tb  = tg[b];
  __syncthreads();

  // ---- S1: gumbel argmax per sample (wave per n), store y/u/mot ----
  for (int n = wid; n < N_; n += 10) {
    const uint32_t p = (uint32_t)(b * N_ + n);
    const int isel = iselS[n];
    const float xi0 = x0L[isel * 3 + 0], xi1 = x0L[isel * 3 + 1], xi2 = x0L[isel * 3 + 2];

    float best = -1e30f; int bestk = 0x7fffffff;
    #pragma unroll
    for (int c2 = 0; c2 < 3; ++c2) {
      const int k = lane + 64 * c2;
      if (k < N_) {
        const uint32_t bits = jax_bits(kj0, kj1, p * 150u + (uint32_t)k);
        float u = __uint_as_float((bits >> 9) | 0x3F800000u) - 1.0f;
        u = fmaxf(u, 1.17549435e-38f);
        const float nlu = -LN2f * LOG2R(u);
        const float g = -LN2f * LOG2R(nlu);
        const float dx = xi0 - x1L[k * 3 + 0];
        const float dy = xi1 - x1L[k * 3 + 1];
        const float dz = xi2 - x1L[k * 3 + 2];
        const float d2 = fmaf(dz, dz, fmaf(dy, dy, dx * dx));
        const float val = fmaf(psiS[k] + nsc * d2, LN2f, g);  // phi_i const over k
        if (val > best || (val == best && k < bestk)) { best = val; bestk = k; }
      }
    }
    #pragma unroll
    for (int off = 1; off < 64; off <<= 1) {
      const float ov = __shfl_xor(best, off);
      const int   ok = __shfl_xor(bestk, off);
      if (ov > best || (ov == best && ok < bestk)) { best = ov; bestk = ok; }
    }
    if (lane == 0) {
      const int j = bestk;
      const float mot = mskS[j];
      const float q0 = x1L[j * 3 + 0], q1 = x1L[j * 3 + 1], q2 = x1L[j * 3 + 2];
      const float omt = 1.f - tb;
      yu[n * 9 + 0] = xi0 * tb + q0 * omt + SIGMAf * epsg[b * 450 + n * 3 + 0];
      yu[n * 9 + 1] = xi1 * tb + q1 * omt + SIGMAf * epsg[b * 450 + n * 3 + 1];
      yu[n * 9 + 2] = xi2 * tb + q2 * omt + SIGMAf * epsg[b * 450 + n * 3 + 2];
      yu[n * 9 + 3] = (xi0 - q0) * mot;
      yu[n * 9 + 4] = (xi1 - q1) * mot;
      yu[n * 9 + 5] = (xi2 - q2) * mot;
      yu[n * 9 + 6] = mot;
    }
  }
  __syncthreads();

  // ---- S2: MLP, lane = sample, hd loop uniform -> scalar W loads ----
  float loss = 0.f;
  if (wid < 3) {
    const int n = wid * 64 + lane;
    if (n < N_) {
      const float y0 = yu[n * 9 + 0], y1 = yu[n * 9 + 1], y2 = yu[n * 9 + 2];
      const float u0 = yu[n * 9 + 3], u1 = yu[n * 9 + 4], u2 = yu[n * 9 + 5];
      const float mot = yu[n * 9 + 6];
      float a0 = 0.f, a1 = 0.f, a2 = 0.f;
      #pragma unroll 4
      for (int hd = 0; hd < 512; ++hd) {
        float z = b1[hd];
        z = fmaf(y0, W1[hd],        z);
        z = fmaf(y1, W1[512 + hd],  z);
        z = fmaf(y2, W1[1024 + hd], z);
        z = fmaf(tb, W1[1536 + hd], z);
        const float zc = fmaf(0.044715f * z, z * z, z);
        const float e2 = EXP2R(-2.3022082062161855f * zc);
        const float ge = z * __builtin_amdgcn_rcpf(1.f + e2);
        a0 = fmaf(ge, W2[hd * 3 + 0], a0);
        a1 = fmaf(ge, W2[hd * 3 + 1], a1);
        a2 = fmaf(ge, W2[hd * 3 + 2], a2);
      }
      const float v0 = (a0 + b2[0]) * mot;
      const float v1 = (a1 + b2[1]) * mot;
      const float v2 = (a2 + b2[2]) * mot;
      const float d0 = v0 - u0, d1 = v1 - u1, d2 = v2 - u2;
      loss = fmaf(d2, d2, fmaf(d1, d1, d0 * d0));
    }
    #pragma unroll
    for (int off = 1; off < 64; off <<= 1) loss += __shfl_xor(loss, off);
    if (lane == 0) red[wid] = loss;
  }
  __syncthreads();
  if (tid == 0) partials[b] = red[0] + red[1] + red[2];
}

__global__ void cfm_reduce_kernel(const float* __restrict__ partials,
                                  float* __restrict__ out) {
  const int tid = threadIdx.x;   // 64 threads
  float s = 0.f;
  #pragma unroll
  for (int q = 0; q < 8; ++q) s += partials[tid + 64 * q];
  #pragma unroll
  for (int off = 1; off < 64; off <<= 1) s += __shfl_xor(s, off);
  if (tid == 0) out[0] = s * (1.0f / 230400.0f);
}

extern "C" void kernel_launch(void* const* d_in, const int* in_sizes, int n_in,
                              void* d_out, int out_size, void* d_ws, size_t ws_size,
                              hipStream_t stream) {
  (void)in_sizes; (void)n_in; (void)out_size; (void)ws_size;
  const float* x    = (const float*)d_in[0];
  const float* mask = (const float*)d_in[1];
  const float* t    = (const float*)d_in[2];
  const float* x0n  = (const float*)d_in[3];
  const float* epsn = (const float*)d_in[4];
  const float* W1   = (const float*)d_in[5];
  const float* b1   = (const float*)d_in[6];
  const float* W2   = (const float*)d_in[7];
  const float* b2   = (const float*)d_in[8];
  float* out = (float*)d_out;

  float* pp       = (float*)d_ws;              // 512 * 152 floats
  float* partials = pp + B_ * PPS;             // 512 floats

  uint32_t ki0, ki1, kj0, kj1, k1r0, k1r1, k2r0, k2r1;
  tf2x32(0u, 42u, 0u, 0u, ki0, ki1);
  tf2x32(0u, 42u, 0u, 1u, kj0, kj1);
  tf2x32(ki0, ki1, 0u, 0u, k1r0, k1r1);
  tf2x32(ki0, ki1, 0u, 1u, k2r0, k2r1);

  cfm_ot_kernel<<<B_, NT, 0, stream>>>(x, x0n, pp);
  cfm_sample_kernel<<<B_, NT, 0, stream>>>(x, mask, t, x0n, epsn, W1, b1, W2, b2,
                                           pp, partials,
                                           kj0, kj1, k1r0, k1r1, k2r0, k2r1);
  cfm_reduce_kernel<<<1, 64, 0, stream>>>(partials, out);
}